// Round 12
// baseline (257.344 us; speedup 1.0000x reference)
//
#include <hip/hip_runtime.h>
#include <stdint.h>

// ---------------------------------------------------------------------------
// Fused transformer block: LN( x + (Attn(xWq+bq, xWk+bk, xWv+bv))Wo + bo )
// B=2, S=2048, E=1024, flat heads G=32, D=64. fp32 in/out, bf16 MFMA.
// Round-11: 2-phase-counted pipeline (stage-before-compute, single barrier,
// double-buffered LDS with literal indices) in BOTH gemm_bt and attn4.
// ---------------------------------------------------------------------------

typedef unsigned short u16;
typedef __attribute__((ext_vector_type(8))) __bf16 bf16x8;
typedef __attribute__((ext_vector_type(4))) float floatx4;

#define QSCALE 0.18033688f  /* (1/sqrt(64)) * log2(e): folded into Q */

__device__ inline u16 f32_to_bf16(float f) {
    unsigned int u = __float_as_uint(f);
    unsigned int r = (u + 0x7FFFu + ((u >> 16) & 1u)) >> 16;
    return (u16)r;
}

// async global->LDS, 16B per lane; LDS dest = wave-uniform base + lane*16
__device__ __forceinline__ void gload_lds16(const u16* g, u16* l) {
    __builtin_amdgcn_global_load_lds(
        (const __attribute__((address_space(1))) void*)g,
        (__attribute__((address_space(3))) void*)l, 16, 0, 0);
}

// ---------------- conversion: x fp32 -> bf16 -------------------------------
__global__ __launch_bounds__(256) void convert_x(const float* __restrict__ in,
                                                 u16* __restrict__ out, int n) {
    int idx = (blockIdx.x * 256 + threadIdx.x) * 8;
    if (idx >= n) return;
    float4 a = *reinterpret_cast<const float4*>(in + idx);
    float4 b = *reinterpret_cast<const float4*>(in + idx + 4);
    int4 o;
    o.x = (int)f32_to_bf16(a.x) | ((int)f32_to_bf16(a.y) << 16);
    o.y = (int)f32_to_bf16(a.z) | ((int)f32_to_bf16(a.w) << 16);
    o.z = (int)f32_to_bf16(b.x) | ((int)f32_to_bf16(b.y) << 16);
    o.w = (int)f32_to_bf16(b.z) | ((int)f32_to_bf16(b.w) << 16);
    *reinterpret_cast<int4*>(out + idx) = o;
}

// ---------------- transpose + convert: W[k][n] fp32 -> Wt[n][k] bf16 -------
__global__ __launch_bounds__(256) void transpose_convert(const float* __restrict__ W,
                                                         u16* __restrict__ Wt, int dim) {
    __shared__ float tile[32][33];
    int bx = blockIdx.x * 32, by = blockIdx.y * 32;
    int tx = threadIdx.x, ty = threadIdx.y;  // block (32, 8)
    for (int i = 0; i < 32; i += 8)
        tile[ty + i][tx] = W[(size_t)(by + ty + i) * dim + bx + tx];
    __syncthreads();
    for (int i = 0; i < 32; i += 8)
        Wt[(size_t)(bx + ty + i) * dim + by + tx] = f32_to_bf16(tile[tx][ty + i]);
}

// ---------------- V [32][2048][64] bf16 -> Vt [32][64][2048] ---------------
__global__ __launch_bounds__(256) void transpose_v(const u16* __restrict__ V,
                                                   u16* __restrict__ Vt) {
    __shared__ __align__(16) u16 t[128 * 72];
    const int tid = threadIdx.x;
    const int kc = blockIdx.x * 128;
    const size_t hb = (size_t)blockIdx.y * 131072;
    for (int j = 0; j < 4; ++j) {
        int idx = tid + j * 256;  // 0..1023
        int row = idx >> 3, seg = idx & 7;
        *reinterpret_cast<int4*>(&t[row * 72 + seg * 8]) =
            *reinterpret_cast<const int4*>(&V[hb + (size_t)(kc + row) * 64 + seg * 8]);
    }
    __syncthreads();
    for (int j = 0; j < 4; ++j) {
        int idx = tid + j * 256;
        int d = idx >> 4, ck = idx & 15;
        u16 tmp[8];
        for (int i = 0; i < 8; ++i) tmp[i] = t[(ck * 8 + i) * 72 + d];
        *reinterpret_cast<int4*>(&Vt[hb + (size_t)d * 2048 + kc + ck * 8]) =
            *reinterpret_cast<int4*>(tmp);
    }
}

// ---------------- GEMM: C[4096,1024] = A[4096,1024] @ Wt^T + bias ----------
// MODE 0: out bf16 = (acc + bias) * (z==0 ? QSCALE : 1). MODE 1: fp32 + resid.
// 2-phase-counted: stage tile t+1 (gload_lds w=16) BEFORE computing tile t,
// single __syncthreads per tile (drain lands after compute -> latency hidden).
// Double-buffered LDS with literal indices. Source-chunk swizzle c^=row&7
// (involution on both staging source and LDS read).
template <int MODE>
__global__ __launch_bounds__(256) void gemm_bt(
    const u16* __restrict__ A,
    const u16* __restrict__ Bt0, const u16* __restrict__ Bt1, const u16* __restrict__ Bt2,
    const float* __restrict__ bias0, const float* __restrict__ bias1, const float* __restrict__ bias2,
    u16* __restrict__ out0, u16* __restrict__ out1, u16* __restrict__ out2,
    const float* __restrict__ resid, float* __restrict__ outf) {
    const int tid = threadIdx.x;
    const int bn = blockIdx.x, bm = blockIdx.y, z = blockIdx.z;

    const u16* Bt;
    const float* bias;
    u16* outb = nullptr;
    if (MODE == 0) {
        Bt   = (z == 0) ? Bt0 : (z == 1) ? Bt1 : Bt2;
        bias = (z == 0) ? bias0 : (z == 1) ? bias1 : bias2;
        outb = (z == 0) ? out0 : (z == 1) ? out1 : out2;
    } else {
        Bt = Bt0; bias = bias0;
    }

    __shared__ __align__(16) u16 As[2][128 * 64];
    __shared__ __align__(16) u16 Bs[2][128 * 64];

    const int lane = tid & 63, w = tid >> 6;
    const int wm = w >> 1, wn = w & 1;
    const int l15 = lane & 15, g = lane >> 4;

    floatx4 acc[4][4];
    for (int m = 0; m < 4; ++m)
        for (int n = 0; n < 4; ++n) acc[m][n] = (floatx4){0.f, 0.f, 0.f, 0.f};

    const size_t abase = (size_t)(bm * 128) * 1024;
    const size_t bbase = (size_t)(bn * 128) * 1024;

#define G_STAGE(KT, B)                                                         \
    for (int jj = 0; jj < 4; ++jj) {                                           \
        int cb  = jj * 256 + w * 64;                                           \
        int idx = cb + lane;                                                   \
        int row = idx >> 3, c = idx & 7;                                       \
        int cs  = c ^ (row & 7);                                               \
        gload_lds16(A  + abase + (size_t)row * 1024 + (KT) * 64 + cs * 8,      \
                    &As[B][(size_t)cb * 8]);                                   \
        gload_lds16(Bt + bbase + (size_t)row * 1024 + (KT) * 64 + cs * 8,      \
                    &Bs[B][(size_t)cb * 8]);                                   \
    }

#define G_COMPUTE(B)                                                           \
    for (int kk = 0; kk < 2; ++kk) {                                           \
        bf16x8 af[4], bfr[4];                                                  \
        for (int m = 0; m < 4; ++m) {                                          \
            int row = wm * 64 + m * 16 + l15;                                  \
            int c   = kk * 4 + g;                                              \
            af[m] = *reinterpret_cast<const bf16x8*>(                          \
                &As[B][row * 64 + ((c ^ (row & 7)) * 8)]);                     \
        }                                                                      \
        for (int n = 0; n < 4; ++n) {                                          \
            int row = wn * 64 + n * 16 + l15;                                  \
            int c   = kk * 4 + g;                                              \
            bfr[n] = *reinterpret_cast<const bf16x8*>(                         \
                &Bs[B][row * 64 + ((c ^ (row & 7)) * 8)]);                     \
        }                                                                      \
        for (int m = 0; m < 4; ++m)                                            \
            for (int n = 0; n < 4; ++n)                                        \
                acc[m][n] = __builtin_amdgcn_mfma_f32_16x16x32_bf16(           \
                    af[m], bfr[n], acc[m][n], 0, 0, 0);                        \
    }

    G_STAGE(0, 0);
    __syncthreads();
    for (int kt = 0; kt < 16; kt += 2) {
        if (kt + 1 < 16) { G_STAGE(kt + 1, 1); }
        G_COMPUTE(0);
        __syncthreads();
        if (kt + 2 < 16) { G_STAGE(kt + 2, 0); }
        G_COMPUTE(1);
        __syncthreads();
    }
#undef G_STAGE
#undef G_COMPUTE

    // epilogue: C/D layout col = lane&15, row = 4*(lane>>4) + r
    const float sc = (MODE == 0 && z == 0) ? QSCALE : 1.0f;
    for (int n = 0; n < 4; ++n) {
        int col  = bn * 128 + wn * 64 + n * 16 + l15;
        float bv = bias[col];
        for (int m = 0; m < 4; ++m) {
            int row0 = bm * 128 + wm * 64 + m * 16 + g * 4;
            for (int r = 0; r < 4; ++r) {
                float v    = (acc[m][n][r] + bv) * sc;
                size_t off = (size_t)(row0 + r) * 1024 + col;
                if (MODE == 0) outb[off] = f32_to_bf16(v);
                else           outf[off] = v + resid[off];
            }
        }
    }
}

// ---------------- flash attention, swapped-QK^T, LDS-staged K/V ------------
// Same structure as round-10 attn3 but 2-phase-counted: stage tile t+1 before
// computing tile t, ONE barrier per tile, double-buffered Ks/Vs (literal idx).
// Grid 512: XCD swizzle L=(bid&7)*64+bid/8 -> 2 heads/XCD (K/V L2-resident).
__global__ __launch_bounds__(256) void attn4_kernel(const u16* __restrict__ Q,
                                                    const u16* __restrict__ K,
                                                    const u16* __restrict__ Vt,
                                                    u16* __restrict__ O) {
    const int tid = threadIdx.x, lane = tid & 63, w = tid >> 6;
    const int l15 = lane & 15, g = lane >> 4;

    const int L    = (blockIdx.x & 7) * 64 + (blockIdx.x >> 3);  // XCD swizzle (512%8==0)
    const int head = L >> 4;          // 16 blocks per head
    const int qb   = L & 15;          // q-block of 128 rows
    const size_t hoff = (size_t)head * 131072;
    const int q0 = qb * 128 + w * 32;

    __shared__ __align__(16) u16 Ks[2][64 * 64];  // [k][d] linear, src-swizzled
    __shared__ __align__(16) u16 Vs[2][64 * 64];  // [d][k] linear, src-swizzled
    __shared__ __align__(16) u16 P[4][32 * 72];   // per-wave P: [32 q][64 k], pad 72
    u16* Pw = P[w];

    bf16x8 qf[2][2];
    for (int m = 0; m < 2; ++m)
        for (int kk = 0; kk < 2; ++kk)
            qf[m][kk] = *reinterpret_cast<const bf16x8*>(
                Q + hoff + (size_t)(q0 + m * 16 + l15) * 64 + kk * 32 + g * 8);

    floatx4 acc[2][4];  // [m][c]: ctx[q=m*16+4g+r][d=c*16+l15]
    for (int m = 0; m < 2; ++m)
        for (int c = 0; c < 4; ++c) acc[m][c] = (floatx4){0.f, 0.f, 0.f, 0.f};
    float mrow[2] = {-3.0e38f, -3.0e38f};
    float lrow[2] = {0.f, 0.f};

#define A_STAGE(KB, B)                                                         \
    for (int j = 0; j < 2; ++j) {                                              \
        int cb  = j * 256 + w * 64;                                            \
        int idx = cb + lane;                                                   \
        int r   = idx >> 3, c = idx & 7;                                       \
        int cs  = c ^ (r & 7);                                                 \
        gload_lds16(K  + hoff + (size_t)((KB) + r) * 64 + cs * 8,              \
                    &Ks[B][(size_t)cb * 8]);                                   \
        gload_lds16(Vt + hoff + (size_t)r * 2048 + (KB) + cs * 8,              \
                    &Vs[B][(size_t)cb * 8]);                                   \
    }

#define A_TILE(B)                                                              \
    {                                                                          \
        floatx4 s[2][4];                                                       \
        for (int kt = 0; kt < 4; ++kt) {                                       \
            int rk = kt * 16 + l15;                                            \
            bf16x8 kf0 = *reinterpret_cast<const bf16x8*>(                     \
                &Ks[B][rk * 64 + ((g ^ (rk & 7)) * 8)]);                       \
            bf16x8 kf1 = *reinterpret_cast<const bf16x8*>(                     \
                &Ks[B][rk * 64 + (((g + 4) ^ (rk & 7)) * 8)]);                 \
            for (int m = 0; m < 2; ++m) {                                      \
                floatx4 a = (floatx4){0.f, 0.f, 0.f, 0.f};                     \
                a = __builtin_amdgcn_mfma_f32_16x16x32_bf16(kf0, qf[m][0], a, 0, 0, 0); \
                a = __builtin_amdgcn_mfma_f32_16x16x32_bf16(kf1, qf[m][1], a, 0, 0, 0); \
                s[m][kt] = a;                                                  \
            }                                                                  \
        }                                                                      \
        float tm[2];                                                           \
        for (int m = 0; m < 2; ++m) {                                          \
            float a = s[m][0][0];                                              \
            for (int kt = 0; kt < 4; ++kt)                                     \
                for (int r = 0; r < 4; ++r) a = fmaxf(a, s[m][kt][r]);         \
            a = fmaxf(a, __shfl_xor(a, 16));                                   \
            a = fmaxf(a, __shfl_xor(a, 32));                                   \
            tm[m] = a;                                                         \
        }                                                                      \
        int grow = (tm[0] > mrow[0] + 8.f) || (tm[1] > mrow[1] + 8.f);         \
        if (__any(grow)) {                                                     \
            for (int m = 0; m < 2; ++m) {                                      \
                float mnew  = fmaxf(mrow[m], tm[m]);                           \
                float alpha = exp2f(mrow[m] - mnew);                           \
                mrow[m] = mnew;                                                \
                lrow[m] *= alpha;                                              \
                float ar[4];                                                   \
                for (int r = 0; r < 4; ++r)                                    \
                    ar[r] = __shfl(alpha, (lane & 48) + 4 * ((lane >> 4) & 3) + r); \
                for (int c = 0; c < 4; ++c)                                    \
                    for (int r = 0; r < 4; ++r) acc[m][c][r] *= ar[r];         \
            }                                                                  \
        }                                                                      \
        for (int m = 0; m < 2; ++m) {                                          \
            u16* pr = Pw + (m * 16 + l15) * 72;                                \
            for (int kt = 0; kt < 4; ++kt) {                                   \
                float p0 = exp2f(s[m][kt][0] - mrow[m]);                       \
                float p1 = exp2f(s[m][kt][1] - mrow[m]);                       \
                float p2 = exp2f(s[m][kt][2] - mrow[m]);                       \
                float p3 = exp2f(s[m][kt][3] - mrow[m]);                       \
                lrow[m] += (p0 + p1) + (p2 + p3);                              \
                union { __bf16 h[4]; uint2 u; } pk;                            \
                pk.h[0] = (__bf16)p0; pk.h[1] = (__bf16)p1;                    \
                pk.h[2] = (__bf16)p2; pk.h[3] = (__bf16)p3;                    \
                *reinterpret_cast<uint2*>(pr + kt * 16 + g * 4) = pk.u;        \
            }                                                                  \
        }                                                                      \
        for (int ks = 0; ks < 2; ++ks) {                                       \
            bf16x8 vf[4];                                                      \
            for (int c = 0; c < 4; ++c) {                                      \
                int rv = c * 16 + l15;                                         \
                int ch = ks * 4 + g;                                           \
                vf[c] = *reinterpret_cast<const bf16x8*>(                      \
                    &Vs[B][rv * 64 + ((ch ^ (rv & 7)) * 8)]);                  \
            }                                                                  \
            for (int m = 0; m < 2; ++m) {                                      \
                bf16x8 pa = *reinterpret_cast<const bf16x8*>(                  \
                    Pw + (m * 16 + l15) * 72 + ks * 32 + g * 8);               \
                for (int c = 0; c < 4; ++c)                                    \
                    acc[m][c] = __builtin_amdgcn_mfma_f32_16x16x32_bf16(       \
                        pa, vf[c], acc[m][c], 0, 0, 0);                        \
            }                                                                  \
        }                                                                      \
    }

    A_STAGE(0, 0);
    __syncthreads();
    for (int kb = 0; kb < 2048; kb += 128) {
        A_STAGE(kb + 64, 1);   // kb+64 <= 1984 always in range
        A_TILE(0);
        __syncthreads();
        if (kb + 128 < 2048) { A_STAGE(kb + 128, 0); }
        A_TILE(1);
        __syncthreads();
    }
#undef A_STAGE
#undef A_TILE

    // ---- epilogue: finish denom, transport to ctx layout, normalize, store
    for (int m = 0; m < 2; ++m) {
        float a = lrow[m];
        a += __shfl_xor(a, 16);
        a += __shfl_xor(a, 32);
        lrow[m] = a;
    }
    for (int m = 0; m < 2; ++m) {
        float lr[4];
        for (int r = 0; r < 4; ++r)
            lr[r] = 1.0f / __shfl(lrow[m], (lane & 48) + 4 * ((lane >> 4) & 3) + r);
        for (int c = 0; c < 4; ++c)
            for (int r = 0; r < 4; ++r) {
                float v = acc[m][c][r] * lr[r];
                O[hoff + (size_t)(q0 + m * 16 + 4 * g + r) * 64 + c * 16 + l15] = f32_to_bf16(v);
            }
    }
}

// ---------------- LayerNorm over rows of 1024 ------------------------------
__global__ __launch_bounds__(256) void ln_kernel(const float* __restrict__ in,
                                                 const float* __restrict__ gamma,
                                                 const float* __restrict__ beta,
                                                 float* __restrict__ out) {
    const int row = blockIdx.x;
    const int tid = threadIdx.x;
    float4 v = *reinterpret_cast<const float4*>(in + (size_t)row * 1024 + tid * 4);
    float s1 = v.x + v.y + v.z + v.w;
    float s2 = v.x * v.x + v.y * v.y + v.z * v.z + v.w * v.w;
    for (int off = 1; off < 64; off <<= 1) {
        s1 += __shfl_xor(s1, off);
        s2 += __shfl_xor(s2, off);
    }
    __shared__ float red[8];
    int w = tid >> 6, lane = tid & 63;
    if (lane == 0) { red[w] = s1; red[4 + w] = s2; }
    __syncthreads();
    s1 = red[0] + red[1] + red[2] + red[3];
    s2 = red[4] + red[5] + red[6] + red[7];
    float mean = s1 * (1.f / 1024.f);
    float var  = s2 * (1.f / 1024.f) - mean * mean;
    float rstd = rsqrtf(var + 1e-5f);
    float4 gm = *reinterpret_cast<const float4*>(gamma + tid * 4);
    float4 bt = *reinterpret_cast<const float4*>(beta + tid * 4);
    float4 o;
    o.x = (v.x - mean) * rstd * gm.x + bt.x;
    o.y = (v.y - mean) * rstd * gm.y + bt.y;
    o.z = (v.z - mean) * rstd * gm.z + bt.z;
    o.w = (v.w - mean) * rstd * gm.w + bt.w;
    *reinterpret_cast<float4*>(out + (size_t)row * 1024 + tid * 4) = o;
}

// ---------------------------------------------------------------------------
// Workspace (48 MiB total):
//   [ 0M, 8M)  xb   bf16 x  (dead after QKV GEMM; reused by Vtb)
//   [ 8M,16M)  wqt/wkt/wvt/wot (2 MiB each)
//   [16M,24M)  Qb   (dead after attn; reused by pre)
//   [24M,32M)  Kb   (dead after attn; reused by pre)
//   [32M,40M)  Vb   (dead after transpose_v)
//   [40M,48M)  Cb
//   [ 0M, 8M)  Vtb  V transposed per head [32][64][2048] (aliases xb)
//   [16M,32M)  pre  fp32 pre-LN buffer (aliases Qb+Kb)
extern "C" void kernel_launch(void* const* d_in, const int* in_sizes, int n_in,
                              void* d_out, int out_size, void* d_ws, size_t ws_size,
                              hipStream_t stream) {
    const float* x     = (const float*)d_in[0];
    const float* wq    = (const float*)d_in[1];
    const float* bq    = (const float*)d_in[2];
    const float* wk    = (const float*)d_in[3];
    const float* bk    = (const float*)d_in[4];
    const float* wv    = (const float*)d_in[5];
    const float* bv    = (const float*)d_in[6];
    const float* wo    = (const float*)d_in[7];
    const float* bo    = (const float*)d_in[8];
    const float* gamma = (const float*)d_in[9];
    const float* beta  = (const float*)d_in[10];
    float* out = (float*)d_out;

    char* ws = (char*)d_ws;
    u16* xb    = (u16*)(ws + 0);
    u16* wqt   = (u16*)(ws + (8u << 20));
    u16* wkt   = (u16*)(ws + (10u << 20));
    u16* wvt   = (u16*)(ws + (12u << 20));
    u16* wot   = (u16*)(ws + (14u << 20));
    u16* Qb    = (u16*)(ws + (16u << 20));
    u16* Kb    = (u16*)(ws + (24u << 20));
    u16* Vb    = (u16*)(ws + (32u << 20));
    u16* Cb    = (u16*)(ws + (40u << 20));
    u16* Vtb   = (u16*)(ws + 0);              // aliases xb (dead after QKV GEMM)
    float* pre = (float*)(ws + (16u << 20));  // aliases Qb+Kb (dead after attn)

    convert_x<<<2048, 256, 0, stream>>>(x, xb, 4194304);
    dim3 tb(32, 8);
    transpose_convert<<<dim3(32, 32), tb, 0, stream>>>(wq, wqt, 1024);
    transpose_convert<<<dim3(32, 32), tb, 0, stream>>>(wk, wkt, 1024);
    transpose_convert<<<dim3(32, 32), tb, 0, stream>>>(wv, wvt, 1024);
    transpose_convert<<<dim3(32, 32), tb, 0, stream>>>(wo, wot, 1024);

    gemm_bt<0><<<dim3(8, 32, 3), 256, 0, stream>>>(xb, wqt, wkt, wvt, bq, bk, bv,
                                                   Qb, Kb, Vb, nullptr, nullptr);

    transpose_v<<<dim3(16, 32), 256, 0, stream>>>(Vb, Vtb);

    attn4_kernel<<<512, 256, 0, stream>>>(Qb, Kb, Vtb, Cb);

    gemm_bt<1><<<dim3(8, 32, 1), 256, 0, stream>>>(Cb, wot, nullptr, nullptr, bo, nullptr, nullptr,
                                                   nullptr, nullptr, nullptr, x, pre);

    ln_kernel<<<4096, 256, 0, stream>>>(pre, gamma, beta, out);
}

// Round 13
// 242.306 us; speedup vs baseline: 1.0621x; 1.0621x over previous
//
#include <hip/hip_runtime.h>
#include <stdint.h>

// ---------------------------------------------------------------------------
// Fused transformer block: LN( x + (Attn(xWq+bq, xWk+bk, xWv+bv))Wo + bo )
// B=2, S=2048, E=1024, flat heads G=32, D=64. fp32 in/out, bf16 MFMA.
// Round-13: GEMM reverted to single-buffer (r10); attention 8 waves x 16 rows
// (2x occupancy, same staging); 4 weight transposes merged into one launch.
// ---------------------------------------------------------------------------

typedef unsigned short u16;
typedef __attribute__((ext_vector_type(8))) __bf16 bf16x8;
typedef __attribute__((ext_vector_type(4))) float floatx4;

#define QSCALE 0.18033688f  /* (1/sqrt(64)) * log2(e): folded into Q */

__device__ inline u16 f32_to_bf16(float f) {
    unsigned int u = __float_as_uint(f);
    unsigned int r = (u + 0x7FFFu + ((u >> 16) & 1u)) >> 16;
    return (u16)r;
}

// async global->LDS, 16B per lane; LDS dest = wave-uniform base + lane*16
__device__ __forceinline__ void gload_lds16(const u16* g, u16* l) {
    __builtin_amdgcn_global_load_lds(
        (const __attribute__((address_space(1))) void*)g,
        (__attribute__((address_space(3))) void*)l, 16, 0, 0);
}

// ---------------- conversion: x fp32 -> bf16 -------------------------------
__global__ __launch_bounds__(256) void convert_x(const float* __restrict__ in,
                                                 u16* __restrict__ out, int n) {
    int idx = (blockIdx.x * 256 + threadIdx.x) * 8;
    if (idx >= n) return;
    float4 a = *reinterpret_cast<const float4*>(in + idx);
    float4 b = *reinterpret_cast<const float4*>(in + idx + 4);
    int4 o;
    o.x = (int)f32_to_bf16(a.x) | ((int)f32_to_bf16(a.y) << 16);
    o.y = (int)f32_to_bf16(a.z) | ((int)f32_to_bf16(a.w) << 16);
    o.z = (int)f32_to_bf16(b.x) | ((int)f32_to_bf16(b.y) << 16);
    o.w = (int)f32_to_bf16(b.z) | ((int)f32_to_bf16(b.w) << 16);
    *reinterpret_cast<int4*>(out + idx) = o;
}

// ------ transpose + convert (4 weights, one launch): W[k][n] -> Wt[n][k] ---
__global__ __launch_bounds__(256) void transpose_convert4(
    const float* __restrict__ W0, const float* __restrict__ W1,
    const float* __restrict__ W2, const float* __restrict__ W3,
    u16* __restrict__ T0, u16* __restrict__ T1,
    u16* __restrict__ T2, u16* __restrict__ T3) {
    const int z = blockIdx.z;
    const float* W = (z == 0) ? W0 : (z == 1) ? W1 : (z == 2) ? W2 : W3;
    u16* Wt       = (z == 0) ? T0 : (z == 1) ? T1 : (z == 2) ? T2 : T3;
    __shared__ float tile[32][33];
    int bx = blockIdx.x * 32, by = blockIdx.y * 32;
    int tx = threadIdx.x, ty = threadIdx.y;  // block (32, 8)
    for (int i = 0; i < 32; i += 8)
        tile[ty + i][tx] = W[(size_t)(by + ty + i) * 1024 + bx + tx];
    __syncthreads();
    for (int i = 0; i < 32; i += 8)
        Wt[(size_t)(bx + ty + i) * 1024 + by + tx] = f32_to_bf16(tile[tx][ty + i]);
}

// ---------------- V [32][2048][64] bf16 -> Vt [32][64][2048] ---------------
__global__ __launch_bounds__(256) void transpose_v(const u16* __restrict__ V,
                                                   u16* __restrict__ Vt) {
    __shared__ __align__(16) u16 t[128 * 72];
    const int tid = threadIdx.x;
    const int kc = blockIdx.x * 128;
    const size_t hb = (size_t)blockIdx.y * 131072;
    for (int j = 0; j < 4; ++j) {
        int idx = tid + j * 256;  // 0..1023
        int row = idx >> 3, seg = idx & 7;
        *reinterpret_cast<int4*>(&t[row * 72 + seg * 8]) =
            *reinterpret_cast<const int4*>(&V[hb + (size_t)(kc + row) * 64 + seg * 8]);
    }
    __syncthreads();
    for (int j = 0; j < 4; ++j) {
        int idx = tid + j * 256;
        int d = idx >> 4, ck = idx & 15;
        u16 tmp[8];
        for (int i = 0; i < 8; ++i) tmp[i] = t[(ck * 8 + i) * 72 + d];
        *reinterpret_cast<int4*>(&Vt[hb + (size_t)d * 2048 + kc + ck * 8]) =
            *reinterpret_cast<int4*>(tmp);
    }
}

// ---------------- GEMM: C[4096,1024] = A[4096,1024] @ Wt^T + bias ----------
// Single-buffer m97 structure (r10 version: best measured). 32 KB LDS,
// 3 blocks/CU. Source-chunk swizzle involution c^=row&7 on stage and read.
template <int MODE>
__global__ __launch_bounds__(256) void gemm_bt(
    const u16* __restrict__ A,
    const u16* __restrict__ Bt0, const u16* __restrict__ Bt1, const u16* __restrict__ Bt2,
    const float* __restrict__ bias0, const float* __restrict__ bias1, const float* __restrict__ bias2,
    u16* __restrict__ out0, u16* __restrict__ out1, u16* __restrict__ out2,
    const float* __restrict__ resid, float* __restrict__ outf) {
    const int tid = threadIdx.x;
    const int bn = blockIdx.x, bm = blockIdx.y, z = blockIdx.z;

    const u16* Bt;
    const float* bias;
    u16* outb = nullptr;
    if (MODE == 0) {
        Bt   = (z == 0) ? Bt0 : (z == 1) ? Bt1 : Bt2;
        bias = (z == 0) ? bias0 : (z == 1) ? bias1 : bias2;
        outb = (z == 0) ? out0 : (z == 1) ? out1 : out2;
    } else {
        Bt = Bt0; bias = bias0;
    }

    __shared__ __align__(16) u16 As[128 * 64];
    __shared__ __align__(16) u16 Bs[128 * 64];

    const int lane = tid & 63, w = tid >> 6;
    const int wm = w >> 1, wn = w & 1;
    const int l15 = lane & 15, g = lane >> 4;

    floatx4 acc[4][4];
    for (int m = 0; m < 4; ++m)
        for (int n = 0; n < 4; ++n) acc[m][n] = (floatx4){0.f, 0.f, 0.f, 0.f};

    const size_t abase = (size_t)(bm * 128) * 1024;
    const size_t bbase = (size_t)(bn * 128) * 1024;

    for (int kt = 0; kt < 16; ++kt) {
        __syncthreads();
        for (int jj = 0; jj < 4; ++jj) {
            int cb  = jj * 256 + w * 64;      // wave-uniform chunk base (8-u16 chunks)
            int idx = cb + lane;              // this lane's chunk
            int row = idx >> 3, c = idx & 7;
            int cs  = c ^ (row & 7);          // pre-swizzled source column
            gload_lds16(A  + abase + (size_t)row * 1024 + kt * 64 + cs * 8, &As[(size_t)cb * 8]);
            gload_lds16(Bt + bbase + (size_t)row * 1024 + kt * 64 + cs * 8, &Bs[(size_t)cb * 8]);
        }
        __syncthreads();
        for (int kk = 0; kk < 2; ++kk) {
            bf16x8 af[4], bfr[4];
            for (int m = 0; m < 4; ++m) {
                int row = wm * 64 + m * 16 + l15;
                int c   = kk * 4 + g;
                af[m] = *reinterpret_cast<const bf16x8*>(&As[row * 64 + ((c ^ (row & 7)) * 8)]);
            }
            for (int n = 0; n < 4; ++n) {
                int row = wn * 64 + n * 16 + l15;
                int c   = kk * 4 + g;
                bfr[n] = *reinterpret_cast<const bf16x8*>(&Bs[row * 64 + ((c ^ (row & 7)) * 8)]);
            }
            for (int m = 0; m < 4; ++m)
                for (int n = 0; n < 4; ++n)
                    acc[m][n] = __builtin_amdgcn_mfma_f32_16x16x32_bf16(af[m], bfr[n], acc[m][n], 0, 0, 0);
        }
    }

    // epilogue: C/D layout col = lane&15, row = 4*(lane>>4) + r
    const float sc = (MODE == 0 && z == 0) ? QSCALE : 1.0f;
    for (int n = 0; n < 4; ++n) {
        int col  = bn * 128 + wn * 64 + n * 16 + l15;
        float bv = bias[col];
        for (int m = 0; m < 4; ++m) {
            int row0 = bm * 128 + wm * 64 + m * 16 + g * 4;
            for (int r = 0; r < 4; ++r) {
                float v    = (acc[m][n][r] + bv) * sc;
                size_t off = (size_t)(row0 + r) * 1024 + col;
                if (MODE == 0) outb[off] = f32_to_bf16(v);
                else           outf[off] = v + resid[off];
            }
        }
    }
}

// ---------------- flash attention: 8 waves x 16 q-rows, LDS-staged K/V -----
// Q,K: [32][2048][64] (Q pre-scaled); Vt: [32][64][2048]; O: [32][2048][64].
// Block 512 = 8 waves, each owns 16 q-rows -> 16 waves/CU (2x round-12).
// Staging work per block UNCHANGED vs 4-wave version (1 K + 1 V chunk/thread).
// Grid 512: XCD swizzle L=(bid&7)*64+bid/8 -> 2 heads/XCD (K/V L2-resident).
// 2-phase: stage tile t+1 before computing tile t, one barrier per tile.
__global__ __launch_bounds__(512) void attn5_kernel(const u16* __restrict__ Q,
                                                    const u16* __restrict__ K,
                                                    const u16* __restrict__ Vt,
                                                    u16* __restrict__ O) {
    const int tid = threadIdx.x, lane = tid & 63, w = tid >> 6;  // w 0..7
    const int l15 = lane & 15, g = lane >> 4;

    const int L    = (blockIdx.x & 7) * 64 + (blockIdx.x >> 3);  // XCD swizzle (512%8==0)
    const int head = L >> 4;          // 16 blocks per head
    const int qb   = L & 15;          // q-block of 128 rows
    const size_t hoff = (size_t)head * 131072;
    const int q0 = qb * 128 + w * 16;

    __shared__ __align__(16) u16 Ks[2][64 * 64];  // [k][d] linear, src-swizzled
    __shared__ __align__(16) u16 Vs[2][64 * 64];  // [d][k] linear, src-swizzled
    __shared__ __align__(16) u16 P[8][16 * 72];   // per-wave P: [16 q][64 k], pad 72
    u16* Pw = P[w];

    bf16x8 qf[2];
    for (int kk = 0; kk < 2; ++kk)
        qf[kk] = *reinterpret_cast<const bf16x8*>(
            Q + hoff + (size_t)(q0 + l15) * 64 + kk * 32 + g * 8);

    floatx4 acc[4];  // [c]: ctx[q=4g+r][d=c*16+l15]
    for (int c = 0; c < 4; ++c) acc[c] = (floatx4){0.f, 0.f, 0.f, 0.f};
    float mrow = -3.0e38f;
    float lrow = 0.f;

#define A_STAGE(KB, B)                                                         \
    {                                                                          \
        int cb  = w * 64;                /* wave-uniform chunk base */         \
        int idx = cb + lane;             /* chunk 0..511 */                    \
        int r   = idx >> 3, c = idx & 7;                                       \
        int cs  = c ^ (r & 7);           /* pre-swizzled source chunk */       \
        gload_lds16(K  + hoff + (size_t)((KB) + r) * 64 + cs * 8,              \
                    &Ks[B][(size_t)cb * 8]);                                   \
        gload_lds16(Vt + hoff + (size_t)r * 2048 + (KB) + cs * 8,              \
                    &Vs[B][(size_t)cb * 8]);                                   \
    }

#define A_TILE(B)                                                              \
    {                                                                          \
        floatx4 s[4];                                                          \
        for (int kt = 0; kt < 4; ++kt) {                                       \
            int rk = kt * 16 + l15;                                            \
            bf16x8 kf0 = *reinterpret_cast<const bf16x8*>(                     \
                &Ks[B][rk * 64 + ((g ^ (rk & 7)) * 8)]);                       \
            bf16x8 kf1 = *reinterpret_cast<const bf16x8*>(                     \
                &Ks[B][rk * 64 + (((g + 4) ^ (rk & 7)) * 8)]);                 \
            floatx4 a = (floatx4){0.f, 0.f, 0.f, 0.f};                         \
            a = __builtin_amdgcn_mfma_f32_16x16x32_bf16(kf0, qf[0], a, 0, 0, 0); \
            a = __builtin_amdgcn_mfma_f32_16x16x32_bf16(kf1, qf[1], a, 0, 0, 0); \
            s[kt] = a;                                                         \
        }                                                                      \
        float tm = s[0][0];                                                    \
        for (int kt = 0; kt < 4; ++kt)                                         \
            for (int r = 0; r < 4; ++r) tm = fmaxf(tm, s[kt][r]);              \
        tm = fmaxf(tm, __shfl_xor(tm, 16));                                    \
        tm = fmaxf(tm, __shfl_xor(tm, 32));                                    \
        if (__any(tm > mrow + 8.f)) {                                          \
            float mnew  = fmaxf(mrow, tm);                                     \
            float alpha = exp2f(mrow - mnew);                                  \
            mrow = mnew;                                                       \
            lrow *= alpha;                                                     \
            float ar[4];                                                       \
            for (int r = 0; r < 4; ++r)                                        \
                ar[r] = __shfl(alpha, (lane & 48) + 4 * ((lane >> 4) & 3) + r);\
            for (int c = 0; c < 4; ++c)                                        \
                for (int r = 0; r < 4; ++r) acc[c][r] *= ar[r];                \
        }                                                                      \
        {                                                                      \
            u16* pr = Pw + l15 * 72;                                           \
            for (int kt = 0; kt < 4; ++kt) {                                   \
                float p0 = exp2f(s[kt][0] - mrow);                             \
                float p1 = exp2f(s[kt][1] - mrow);                             \
                float p2 = exp2f(s[kt][2] - mrow);                             \
                float p3 = exp2f(s[kt][3] - mrow);                             \
                lrow += (p0 + p1) + (p2 + p3);                                 \
                union { __bf16 h[4]; uint2 u; } pk;                            \
                pk.h[0] = (__bf16)p0; pk.h[1] = (__bf16)p1;                    \
                pk.h[2] = (__bf16)p2; pk.h[3] = (__bf16)p3;                    \
                *reinterpret_cast<uint2*>(pr + kt * 16 + g * 4) = pk.u;        \
            }                                                                  \
        }                                                                      \
        for (int ks = 0; ks < 2; ++ks) {                                       \
            bf16x8 pa = *reinterpret_cast<const bf16x8*>(                      \
                Pw + l15 * 72 + ks * 32 + g * 8);                              \
            for (int c = 0; c < 4; ++c) {                                      \
                int rv = c * 16 + l15;                                         \
                int ch = ks * 4 + g;                                           \
                bf16x8 vf = *reinterpret_cast<const bf16x8*>(                  \
                    &Vs[B][rv * 64 + ((ch ^ (rv & 7)) * 8)]);                  \
                acc[c] = __builtin_amdgcn_mfma_f32_16x16x32_bf16(              \
                    pa, vf, acc[c], 0, 0, 0);                                  \
            }                                                                  \
        }                                                                      \
    }

    A_STAGE(0, 0);
    __syncthreads();
    for (int kb = 0; kb < 2048; kb += 128) {
        A_STAGE(kb + 64, 1);   // kb+64 <= 1984 always in range
        A_TILE(0);
        __syncthreads();
        if (kb + 128 < 2048) { A_STAGE(kb + 128, 0); }
        A_TILE(1);
        __syncthreads();
    }
#undef A_STAGE
#undef A_TILE

    // ---- epilogue: finish denom, transport to ctx layout, normalize, store
    lrow += __shfl_xor(lrow, 16);
    lrow += __shfl_xor(lrow, 32);
    float lr[4];
    for (int r = 0; r < 4; ++r)
        lr[r] = 1.0f / __shfl(lrow, (lane & 48) + 4 * ((lane >> 4) & 3) + r);
    for (int c = 0; c < 4; ++c)
        for (int r = 0; r < 4; ++r) {
            float v = acc[c][r] * lr[r];
            O[hoff + (size_t)(q0 + 4 * g + r) * 64 + c * 16 + l15] = f32_to_bf16(v);
        }
}

// ---------------- LayerNorm over rows of 1024 ------------------------------
__global__ __launch_bounds__(256) void ln_kernel(const float* __restrict__ in,
                                                 const float* __restrict__ gamma,
                                                 const float* __restrict__ beta,
                                                 float* __restrict__ out) {
    const int row = blockIdx.x;
    const int tid = threadIdx.x;
    float4 v = *reinterpret_cast<const float4*>(in + (size_t)row * 1024 + tid * 4);
    float s1 = v.x + v.y + v.z + v.w;
    float s2 = v.x * v.x + v.y * v.y + v.z * v.z + v.w * v.w;
    for (int off = 1; off < 64; off <<= 1) {
        s1 += __shfl_xor(s1, off);
        s2 += __shfl_xor(s2, off);
    }
    __shared__ float red[8];
    int w = tid >> 6, lane = tid & 63;
    if (lane == 0) { red[w] = s1; red[4 + w] = s2; }
    __syncthreads();
    s1 = red[0] + red[1] + red[2] + red[3];
    s2 = red[4] + red[5] + red[6] + red[7];
    float mean = s1 * (1.f / 1024.f);
    float var  = s2 * (1.f / 1024.f) - mean * mean;
    float rstd = rsqrtf(var + 1e-5f);
    float4 gm = *reinterpret_cast<const float4*>(gamma + tid * 4);
    float4 bt = *reinterpret_cast<const float4*>(beta + tid * 4);
    float4 o;
    o.x = (v.x - mean) * rstd * gm.x + bt.x;
    o.y = (v.y - mean) * rstd * gm.y + bt.y;
    o.z = (v.z - mean) * rstd * gm.z + bt.z;
    o.w = (v.w - mean) * rstd * gm.w + bt.w;
    *reinterpret_cast<float4*>(out + (size_t)row * 1024 + tid * 4) = o;
}

// ---------------------------------------------------------------------------
// Workspace (48 MiB total):
//   [ 0M, 8M)  xb   bf16 x  (dead after QKV GEMM; reused by Vtb)
//   [ 8M,16M)  wqt/wkt/wvt/wot (2 MiB each)
//   [16M,24M)  Qb   (dead after attn; reused by pre)
//   [24M,32M)  Kb   (dead after attn; reused by pre)
//   [32M,40M)  Vb   (dead after transpose_v)
//   [40M,48M)  Cb
//   [ 0M, 8M)  Vtb  V transposed per head [32][64][2048] (aliases xb)
//   [16M,32M)  pre  fp32 pre-LN buffer (aliases Qb+Kb)
extern "C" void kernel_launch(void* const* d_in, const int* in_sizes, int n_in,
                              void* d_out, int out_size, void* d_ws, size_t ws_size,
                              hipStream_t stream) {
    const float* x     = (const float*)d_in[0];
    const float* wq    = (const float*)d_in[1];
    const float* bq    = (const float*)d_in[2];
    const float* wk    = (const float*)d_in[3];
    const float* bk    = (const float*)d_in[4];
    const float* wv    = (const float*)d_in[5];
    const float* bv    = (const float*)d_in[6];
    const float* wo    = (const float*)d_in[7];
    const float* bo    = (const float*)d_in[8];
    const float* gamma = (const float*)d_in[9];
    const float* beta  = (const float*)d_in[10];
    float* out = (float*)d_out;

    char* ws = (char*)d_ws;
    u16* xb    = (u16*)(ws + 0);
    u16* wqt   = (u16*)(ws + (8u << 20));
    u16* wkt   = (u16*)(ws + (10u << 20));
    u16* wvt   = (u16*)(ws + (12u << 20));
    u16* wot   = (u16*)(ws + (14u << 20));
    u16* Qb    = (u16*)(ws + (16u << 20));
    u16* Kb    = (u16*)(ws + (24u << 20));
    u16* Vb    = (u16*)(ws + (32u << 20));
    u16* Cb    = (u16*)(ws + (40u << 20));
    u16* Vtb   = (u16*)(ws + 0);              // aliases xb (dead after QKV GEMM)
    float* pre = (float*)(ws + (16u << 20));  // aliases Qb+Kb (dead after attn)

    convert_x<<<2048, 256, 0, stream>>>(x, xb, 4194304);
    dim3 tb(32, 8);
    transpose_convert4<<<dim3(32, 32, 4), tb, 0, stream>>>(wq, wk, wv, wo,
                                                           wqt, wkt, wvt, wot);

    gemm_bt<0><<<dim3(8, 32, 3), 256, 0, stream>>>(xb, wqt, wkt, wvt, bq, bk, bv,
                                                   Qb, Kb, Vb, nullptr, nullptr);

    transpose_v<<<dim3(16, 32), 256, 0, stream>>>(Vb, Vtb);

    attn5_kernel<<<512, 512, 0, stream>>>(Qb, Kb, Vtb, Cb);

    gemm_bt<1><<<dim3(8, 32, 1), 256, 0, stream>>>(Cb, wot, nullptr, nullptr, bo, nullptr, nullptr,
                                                   nullptr, nullptr, nullptr, x, pre);

    ln_kernel<<<4096, 256, 0, stream>>>(pre, gamma, beta, out);
}